// Round 1
// baseline (229.793 us; speedup 1.0000x reference)
//
#include <hip/hip_runtime.h>
#include <math.h>

// Problem constants (static per reference)
#define N_NODES 262144      // B * NPG
#define NPG     512
#define B_GR    512
#define FDIM    255
#define DEG     32
#define EPG     (NPG * DEG)     // 16384 edges per graph (graph-contiguous)
#define E_TOT   (N_NODES * DEG) // 8388608
#define K_KEEP  256             // ceil(0.5 * NPG)

// ---------------------------------------------------------------------------
// K1: per-node GCN input projection  h[i] = sum_f feat[i,f]*W[f] + real_i*W[255]
// One wave (64 lanes) per node; lane covers f = lane + 64k (coalesced dwords).
// ---------------------------------------------------------------------------
__global__ __launch_bounds__(256) void k_proj(const float* __restrict__ feat,
                                              const int*   __restrict__ z,
                                              const float* __restrict__ W,
                                              float*       __restrict__ h) {
    __shared__ float Wl[256];
    const int tid = threadIdx.x;
    Wl[tid] = W[tid];          // block is exactly 256 threads
    __syncthreads();

    const int wave = tid >> 6;
    const int lane = tid & 63;
    const int node = blockIdx.x * 4 + wave;

    const float* row = feat + (size_t)node * FDIM;
    float acc = 0.f;
#pragma unroll
    for (int k = 0; k < 4; ++k) {
        const int f = lane + k * 64;
        if (f < FDIM) {
            acc = fmaf(row[f], Wl[f], acc);
        } else {
            // f == 255 (lane 63, k==3): the appended real/virtual bit
            const float real = (z[node] != 100) ? 1.f : 0.f;
            acc = fmaf(real, Wl[255], acc);
        }
    }
#pragma unroll
    for (int off = 32; off; off >>= 1)
        acc += __shfl_down(acc, off, 64);
    if (lane == 0) h[node] = acc;
}

// ---------------------------------------------------------------------------
// K2: one block (512 threads) per graph.
//   deg (LDS atomics) -> dinv -> agg (LDS float atomics) -> tanh score
//   -> rank-count top-K (jax tie-break: lower index wins on equal score)
//   -> gated gather-mean into d_out[g, 0:256]
// ---------------------------------------------------------------------------
__global__ __launch_bounds__(512) void k_pool(const float* __restrict__ feat,
                                              const int*   __restrict__ z,
                                              const int*   __restrict__ ei,
                                              const float* __restrict__ bias,
                                              const float* __restrict__ h,
                                              float*       __restrict__ outp) {
    __shared__ float h_l[NPG];
    __shared__ float dinv[NPG];
    __shared__ float agg[NPG];
    __shared__ float score[NPG];
    __shared__ float realb[NPG];
    __shared__ int   deg[NPG];
    __shared__ int   sel_idx[K_KEEP];
    __shared__ float sel_sc[K_KEEP];
    __shared__ float red[256];
    __shared__ int   cnt;

    const int g     = blockIdx.x;
    const int tid   = threadIdx.x;
    const int nbase = g * NPG;

    h_l[tid]   = h[nbase + tid];
    realb[tid] = (z[nbase + tid] != 100) ? 1.f : 0.f;
    deg[tid]   = 1;                       // self-loop
    agg[tid]   = 0.f;
    if (tid == 0) cnt = 0;
    __syncthreads();

    const int* rowp = ei + (size_t)g * EPG;            // edge_index[0]
    const int* colp = ei + (size_t)E_TOT + (size_t)g * EPG; // edge_index[1]

    // pass 1: in-degree
    for (int e = tid; e < EPG; e += NPG)
        atomicAdd(&deg[colp[e] - nbase], 1);
    __syncthreads();

    // correctly-rounded f32 rsqrt (match numpy 1/sqrt within 1 ulp)
    dinv[tid] = (float)(1.0 / sqrt((double)deg[tid]));
    __syncthreads();

    // pass 2: weighted aggregation  agg[c] += dinv[r]*dinv[c]*h[r]
    for (int e = tid; e < EPG; e += NPG) {
        const int r = rowp[e] - nbase;
        const int c = colp[e] - nbase;
        atomicAdd(&agg[c], dinv[r] * dinv[c] * h_l[r]);
    }
    __syncthreads();

    const float sc = tanhf(agg[tid] + dinv[tid] * dinv[tid] * h_l[tid] + bias[0]);
    score[tid] = sc;
    __syncthreads();

    // rank-count top-K: selected iff fewer than K nodes beat me
    int rank = 0;
    for (int j = 0; j < NPG; ++j) {
        const float sj = score[j];      // broadcast read
        rank += (sj > sc) || (sj == sc && j < tid);
    }
    if (rank < K_KEEP) {
        const int slot = atomicAdd(&cnt, 1);
        sel_idx[slot] = tid;
        sel_sc[slot]  = sc;
    }
    __syncthreads();

    // gated mean pool: out[g,f] = (1/K) * sum_sel score_s * x[node_s, f]
    const int f    = tid & 255;
    const int half = tid >> 8;
    float acc = 0.f;
    if (f < FDIM) {
        for (int s = half; s < K_KEEP; s += 2) {
            const int node = sel_idx[s];            // LDS broadcast
            acc = fmaf(sel_sc[s], feat[(size_t)(nbase + node) * FDIM + f], acc);
        }
    } else {                                        // f == 255: real bit
        for (int s = half; s < K_KEEP; s += 2)
            acc = fmaf(sel_sc[s], realb[sel_idx[s]], acc);
    }
    if (half == 1) red[f] = acc;
    __syncthreads();
    if (half == 0)
        outp[(size_t)g * 256 + f] = (acc + red[f]) * (1.f / K_KEEP);
}

extern "C" void kernel_launch(void* const* d_in, const int* in_sizes, int n_in,
                              void* d_out, int out_size, void* d_ws, size_t ws_size,
                              hipStream_t stream) {
    const float* feat = (const float*)d_in[0];   // out: [N, F] f32
    const int*   z    = (const int*)  d_in[1];   // z:   [N] i32
    const int*   ei   = (const int*)  d_in[2];   // edge_index: [2, E] i32
    // d_in[3] = batch (unused), d_in[6] = edge_attr (unused)
    const float* W    = (const float*)d_in[4];   // [F+1] f32
    const float* bias = (const float*)d_in[5];   // [1] f32
    float* outp = (float*)d_out;                 // [B, F+1] f32
    float* h    = (float*)d_ws;                  // N floats scratch

    k_proj<<<N_NODES / 4, 256, 0, stream>>>(feat, z, W, h);
    k_pool<<<B_GR, 512, 0, stream>>>(feat, z, ei, bias, h, outp);
}

// Round 2
// 130.258 us; speedup vs baseline: 1.7641x; 1.7641x over previous
//
#include <hip/hip_runtime.h>
#include <math.h>

// Problem constants (static per reference)
#define NPG     512
#define B_GR    512
#define FDIM    255
#define DEG     32
#define EPG     (NPG * DEG)       // 16384 edges per graph (graph-contiguous)
#define N_NODES (B_GR * NPG)      // 262144
#define E_TOT   (N_NODES * DEG)   // 8388608
#define K_KEEP  256               // ceil(0.5 * NPG)

#define NPB   32                  // nodes per k_proj block
#define FPB   (NPB * FDIM)        // 8160 floats staged per block
#define F4PB  (FPB / 4)           // 2040 float4s (32-node group is 16B aligned)

// ---------------------------------------------------------------------------
// K1: h[i] = feat[i,:]·W[0:255] + real_i·W[255]
// 512 threads / 32 nodes per block. Stage rows via float4 (16B/lane) into
// LDS, then each of 8 waves dot-products 4 nodes from LDS + shfl reduce.
// ---------------------------------------------------------------------------
__global__ __launch_bounds__(512) void k_proj(const float* __restrict__ feat,
                                              const int*   __restrict__ z,
                                              const float* __restrict__ W,
                                              float*       __restrict__ h) {
    __shared__ float4 stage4[F4PB];
    __shared__ float  Wl[256];
    __shared__ float  realw[NPB];    // real_bit * W[255] per node

    const int tid   = threadIdx.x;
    const int nbase = blockIdx.x * NPB;

    if (tid < 256) Wl[tid] = W[tid];
    if (tid < NPB) realw[tid] = (z[nbase + tid] != 100) ? W[FDIM] : 0.f;

    const float4* src = (const float4*)(feat + (size_t)nbase * FDIM);
#pragma unroll
    for (int it = 0; it < 4; ++it) {
        const int idx = it * 512 + tid;
        if (idx < F4PB) stage4[idx] = src[idx];
    }
    __syncthreads();

    const float* stage = (const float*)stage4;
    const int wave = tid >> 6;
    const int lane = tid & 63;
#pragma unroll
    for (int k = 0; k < 4; ++k) {
        const int node = wave * 4 + k;
        const float* row = stage + node * FDIM;
        float acc = (lane == 0) ? realw[node] : 0.f;
        acc = fmaf(row[lane],       Wl[lane],       acc);
        acc = fmaf(row[lane + 64],  Wl[lane + 64],  acc);
        acc = fmaf(row[lane + 128], Wl[lane + 128], acc);
        if (lane < 63)
            acc = fmaf(row[lane + 192], Wl[lane + 192], acc);
#pragma unroll
        for (int off = 32; off; off >>= 1)
            acc += __shfl_down(acc, off, 64);
        if (lane == 0) h[nbase + node] = acc;
    }
}

// ---------------------------------------------------------------------------
// K2: one block (1024 threads = 16 waves -> 2 blocks/CU = 100% occupancy)
// per graph: deg -> dinv -> agg -> tanh score -> rank-count top-K ->
// gated gather-mean. int4 edge loads (4 edges / lane / inst).
// ---------------------------------------------------------------------------
__global__ __launch_bounds__(1024) void k_score(const float* __restrict__ feat,
                                                const int*   __restrict__ z,
                                                const int*   __restrict__ ei,
                                                const float* __restrict__ bias,
                                                const float* __restrict__ h,
                                                float*       __restrict__ outp) {
    __shared__ float h_l[NPG];
    __shared__ float dinv_l[NPG];
    __shared__ float agg[NPG];
    __shared__ float score[NPG];
    __shared__ float realb[NPG];
    __shared__ int   deg[NPG];
    __shared__ int   rank2[2][NPG];
    __shared__ int   selidx[K_KEEP];
    __shared__ float selsc[K_KEEP];
    __shared__ float red[3][256];
    __shared__ int   cnt;

    const int g     = blockIdx.x;
    const int tid   = threadIdx.x;
    const int nbase = g * NPG;

    if (tid < NPG) {
        h_l[tid] = h[nbase + tid];
        deg[tid] = 1;                 // self-loop
        agg[tid] = 0.f;
    } else {
        const int t = tid - NPG;
        realb[t] = (z[nbase + t] != 100) ? 1.f : 0.f;
    }
    if (tid == 0) cnt = 0;
    __syncthreads();

    const int4* colp4 = (const int4*)(ei + (size_t)E_TOT + (size_t)g * EPG);
    const int4* rowp4 = (const int4*)(ei + (size_t)g * EPG);

    // pass 1: in-degree (4 int4 loads per thread)
#pragma unroll
    for (int it = 0; it < 4; ++it) {
        const int4 c4 = colp4[it * 1024 + tid];
        atomicAdd(&deg[c4.x - nbase], 1);
        atomicAdd(&deg[c4.y - nbase], 1);
        atomicAdd(&deg[c4.z - nbase], 1);
        atomicAdd(&deg[c4.w - nbase], 1);
    }
    __syncthreads();

    if (tid < NPG)
        dinv_l[tid] = (float)(1.0 / sqrt((double)deg[tid]));
    __syncthreads();

    // pass 2: weighted aggregation
#pragma unroll
    for (int it = 0; it < 4; ++it) {
        const int4 r4 = rowp4[it * 1024 + tid];
        const int4 c4 = colp4[it * 1024 + tid];
        int r, c;
        r = r4.x - nbase; c = c4.x - nbase; atomicAdd(&agg[c], dinv_l[r] * dinv_l[c] * h_l[r]);
        r = r4.y - nbase; c = c4.y - nbase; atomicAdd(&agg[c], dinv_l[r] * dinv_l[c] * h_l[r]);
        r = r4.z - nbase; c = c4.z - nbase; atomicAdd(&agg[c], dinv_l[r] * dinv_l[c] * h_l[r]);
        r = r4.w - nbase; c = c4.w - nbase; atomicAdd(&agg[c], dinv_l[r] * dinv_l[c] * h_l[r]);
    }
    __syncthreads();

    if (tid < NPG)
        score[tid] = tanhf(agg[tid] + dinv_l[tid] * dinv_l[tid] * h_l[tid] + bias[0]);
    __syncthreads();

    // rank-count top-K, split across two 512-thread halves
    {
        const int node = tid & (NPG - 1);
        const int half = tid >> 9;
        const float sc = score[node];
        const int j0   = half * 256;
        int part = 0;
        for (int i = 0; i < 256; ++i) {
            const int j = j0 + i;
            const float sj = score[j];          // broadcast read
            part += (sj > sc) || (sj == sc && j < node);
        }
        rank2[half][node] = part;
    }
    __syncthreads();

    if (tid < NPG) {
        const int rank = rank2[0][tid] + rank2[1][tid];
        if (rank < K_KEEP) {                    // jax tie-break: lower idx wins
            const int slot = atomicAdd(&cnt, 1);
            selidx[slot] = tid;
            selsc[slot]  = score[tid];
        }
    }
    __syncthreads();

    // gated mean pool: 4 quarters of 256 threads each cover s = q, q+4, ...
    const int f = tid & 255;
    const int q = tid >> 8;
    float acc = 0.f;
    if (f < FDIM) {
        const float* fb = feat + (size_t)nbase * FDIM + f;
#pragma unroll 8
        for (int s = q; s < K_KEEP; s += 4)
            acc = fmaf(selsc[s], fb[(size_t)selidx[s] * FDIM], acc);
    } else {
#pragma unroll 8
        for (int s = q; s < K_KEEP; s += 4)
            acc = fmaf(selsc[s], realb[selidx[s]], acc);
    }
    if (q) red[q - 1][f] = acc;
    __syncthreads();
    if (q == 0)
        outp[(size_t)g * 256 + f] =
            (acc + red[0][f] + red[1][f] + red[2][f]) * (1.f / K_KEEP);
}

extern "C" void kernel_launch(void* const* d_in, const int* in_sizes, int n_in,
                              void* d_out, int out_size, void* d_ws, size_t ws_size,
                              hipStream_t stream) {
    const float* feat = (const float*)d_in[0];   // out: [N, F] f32
    const int*   z    = (const int*)  d_in[1];   // z:   [N] i32
    const int*   ei   = (const int*)  d_in[2];   // edge_index: [2, E] i32
    // d_in[3] = batch (unused), d_in[6] = edge_attr (unused)
    const float* W    = (const float*)d_in[4];   // [F+1] f32
    const float* bias = (const float*)d_in[5];   // [1] f32
    float* outp = (float*)d_out;                 // [B, F+1] f32
    float* h    = (float*)d_ws;                  // N floats scratch

    k_proj<<<N_NODES / NPB, 512, 0, stream>>>(feat, z, W, h);
    k_score<<<B_GR, 1024, 0, stream>>>(feat, z, ei, bias, h, outp);
}

// Round 3
// 128.733 us; speedup vs baseline: 1.7850x; 1.0118x over previous
//
#include <hip/hip_runtime.h>
#include <math.h>

// Problem constants (static per reference)
#define NPG     512
#define B_GR    512
#define FDIM    255
#define DEG     32
#define EPG     (NPG * DEG)       // 16384 edges per graph (graph-contiguous)
#define N_NODES (B_GR * NPG)      // 262144
#define E_TOT   (N_NODES * DEG)   // 8388608
#define K_KEEP  256               // ceil(0.5 * NPG)

#define CH_NODES 32                       // nodes staged per chunk in phase A
#define CH_F4    ((CH_NODES * FDIM) / 4)  // 2040 float4 per chunk (16B aligned)
#define NCHUNK   (NPG / CH_NODES)         // 16

// ---------------------------------------------------------------------------
// One 1024-thread block per graph. Phases:
//  A: h[i] = feat[i,:]·W + real_i·W[255]   (float4 LDS staging, LDS dot)
//  B: deg (col read once, cached as ushort in LDS) -> dinv -> agg (row read)
//  C: tanh score -> rank-count top-K (jax tie-break)
//  D: gated gather-mean into d_out[g, 0:256]
// ---------------------------------------------------------------------------
__global__ __launch_bounds__(1024) void k_fused(const float* __restrict__ feat,
                                                const int*   __restrict__ z,
                                                const int*   __restrict__ ei,
                                                const float* __restrict__ W,
                                                const float* __restrict__ bias,
                                                float*       __restrict__ outp) {
    // phase A: float4 stage (32640B); phase B: ushort col cache (32768B)
    __shared__ __align__(16) char stagebuf[32768];
    __shared__ float Wl[256];
    __shared__ float h_l[NPG];
    __shared__ float dinv_l[NPG];
    __shared__ float agg[NPG];
    __shared__ float score[NPG];
    __shared__ float realb[NPG];
    __shared__ int   deg[NPG];
    __shared__ int   rank2[2][NPG];
    __shared__ int   selidx[K_KEEP];
    __shared__ float selsc[K_KEEP];
    __shared__ float red[3][256];
    __shared__ int   cnt;

    const int g     = blockIdx.x;
    const int tid   = threadIdx.x;
    const int nbase = g * NPG;

    if (tid < 256) Wl[tid] = W[tid];
    if (tid < NPG) {
        realb[tid] = (z[nbase + tid] != 100) ? 1.f : 0.f;
        deg[tid]   = 1;                   // self-loop
        agg[tid]   = 0.f;
    }
    if (tid == 0) cnt = 0;
    __syncthreads();

    // ---------------- Phase A: projection h ----------------
    {
        float4*      stage4 = (float4*)stagebuf;
        const float* stage  = (const float*)stagebuf;
        const int    wave   = tid >> 6;
        const int    lane   = tid & 63;
        const float4* src   = (const float4*)(feat + (size_t)nbase * FDIM);

        for (int ch = 0; ch < NCHUNK; ++ch) {
            stage4[tid] = src[ch * CH_F4 + tid];              // tid < 1024 < 2040
            const int idx2 = 1024 + tid;
            if (idx2 < CH_F4) stage4[idx2] = src[ch * CH_F4 + idx2];
            __syncthreads();
#pragma unroll
            for (int k = 0; k < 2; ++k) {
                const int node = wave * 2 + k;                // 0..31
                const float* row = stage + node * FDIM;
                float acc = (lane == 0) ? realb[ch * CH_NODES + node] * Wl[FDIM] : 0.f;
                acc = fmaf(row[lane],       Wl[lane],       acc);
                acc = fmaf(row[lane + 64],  Wl[lane + 64],  acc);
                acc = fmaf(row[lane + 128], Wl[lane + 128], acc);
                if (lane < 63)
                    acc = fmaf(row[lane + 192], Wl[lane + 192], acc);
#pragma unroll
                for (int off = 32; off; off >>= 1)
                    acc += __shfl_down(acc, off, 64);
                if (lane == 0) h_l[ch * CH_NODES + node] = acc;
            }
            __syncthreads();   // protect stage before next chunk / phase B reuse
        }
    }

    // ---------------- Phase B: degree + aggregation ----------------
    {
        ushort4*    cc4   = (ushort4*)stagebuf;   // local col cache
        const int4* colp4 = (const int4*)(ei + (size_t)E_TOT + (size_t)g * EPG);
        const int4* rowp4 = (const int4*)(ei + (size_t)g * EPG);

#pragma unroll
        for (int it = 0; it < 4; ++it) {
            const int  idx = it * 1024 + tid;
            const int4 c4  = colp4[idx];
            ushort4 u;
            u.x = (unsigned short)(c4.x - nbase);
            u.y = (unsigned short)(c4.y - nbase);
            u.z = (unsigned short)(c4.z - nbase);
            u.w = (unsigned short)(c4.w - nbase);
            cc4[idx] = u;
            atomicAdd(&deg[u.x], 1);
            atomicAdd(&deg[u.y], 1);
            atomicAdd(&deg[u.z], 1);
            atomicAdd(&deg[u.w], 1);
        }
        __syncthreads();

        if (tid < NPG)   // correctly-rounded f32 rsqrt (match np within 1 ulp)
            dinv_l[tid] = (float)(1.0 / sqrt((double)deg[tid]));
        __syncthreads();

#pragma unroll
        for (int it = 0; it < 4; ++it) {
            const int     idx = it * 1024 + tid;
            const int4    r4  = rowp4[idx];
            const ushort4 u   = cc4[idx];
            int r;
            r = r4.x - nbase; atomicAdd(&agg[u.x], dinv_l[r] * dinv_l[u.x] * h_l[r]);
            r = r4.y - nbase; atomicAdd(&agg[u.y], dinv_l[r] * dinv_l[u.y] * h_l[r]);
            r = r4.z - nbase; atomicAdd(&agg[u.z], dinv_l[r] * dinv_l[u.z] * h_l[r]);
            r = r4.w - nbase; atomicAdd(&agg[u.w], dinv_l[r] * dinv_l[u.w] * h_l[r]);
        }
        __syncthreads();
    }

    // ---------------- Phase C: score + top-K selection ----------------
    if (tid < NPG)
        score[tid] = tanhf(agg[tid] + dinv_l[tid] * dinv_l[tid] * h_l[tid] + bias[0]);
    __syncthreads();

    {
        const int   node = tid & (NPG - 1);
        const int   half = tid >> 9;
        const float sc   = score[node];
        const int   j0   = half * 256;
        int part = 0;
        for (int i = 0; i < 256; ++i) {
            const int   j  = j0 + i;
            const float sj = score[j];            // broadcast read
            part += (sj > sc) || (sj == sc && j < node);
        }
        rank2[half][node] = part;
    }
    __syncthreads();

    if (tid < NPG) {
        const int rank = rank2[0][tid] + rank2[1][tid];
        if (rank < K_KEEP) {                      // jax tie-break: lower idx wins
            const int slot = atomicAdd(&cnt, 1);
            selidx[slot] = tid;
            selsc[slot]  = score[tid];
        }
    }
    __syncthreads();

    // ---------------- Phase D: gated gather-mean ----------------
    {
        const int f = tid & 255;
        const int q = tid >> 8;                   // 4 quarters
        float acc = 0.f;
        if (f < FDIM) {
            const float* fb = feat + (size_t)nbase * FDIM + f;
#pragma unroll 8
            for (int s = q; s < K_KEEP; s += 4)
                acc = fmaf(selsc[s], fb[(size_t)selidx[s] * FDIM], acc);
        } else {
#pragma unroll 8
            for (int s = q; s < K_KEEP; s += 4)
                acc = fmaf(selsc[s], realb[selidx[s]], acc);
        }
        if (q) red[q - 1][f] = acc;
        __syncthreads();
        if (q == 0)
            outp[(size_t)g * 256 + f] =
                (acc + red[0][f] + red[1][f] + red[2][f]) * (1.f / K_KEEP);
    }
}

extern "C" void kernel_launch(void* const* d_in, const int* in_sizes, int n_in,
                              void* d_out, int out_size, void* d_ws, size_t ws_size,
                              hipStream_t stream) {
    const float* feat = (const float*)d_in[0];   // out: [N, F] f32
    const int*   z    = (const int*)  d_in[1];   // z:   [N] i32
    const int*   ei   = (const int*)  d_in[2];   // edge_index: [2, E] i32
    // d_in[3] = batch (unused), d_in[6] = edge_attr (unused)
    const float* W    = (const float*)d_in[4];   // [F+1] f32
    const float* bias = (const float*)d_in[5];   // [1] f32
    float* outp = (float*)d_out;                 // [B, F+1] f32

    k_fused<<<B_GR, 1024, 0, stream>>>(feat, z, ei, W, bias, outp);
}

// Round 4
// 118.431 us; speedup vs baseline: 1.9403x; 1.0870x over previous
//
#include <hip/hip_runtime.h>
#include <math.h>

// Problem constants (static per reference)
#define NPG     512
#define B_GR    512
#define FDIM    255
#define DEG     32
#define EPG     (NPG * DEG)       // 16384 edges per graph (graph-contiguous)
#define N_NODES (B_GR * NPG)      // 262144
#define E_TOT   (N_NODES * DEG)   // 8388608
#define K_KEEP  256               // ceil(0.5 * NPG)

#define CH_NODES 16                        // nodes per phase-A chunk
#define CH_FLOATS (CH_NODES * FDIM)        // 4080 floats = 16320 B
#define CH_F4     (CH_FLOATS / 4)          // 1020 float4 DMA ops per chunk
#define NCHUNK    (NPG / CH_NODES)         // 32

// direct global->LDS DMA, 16 B per lane (dest = wave-uniform base + lane*16)
__device__ __forceinline__ void lds_dma16(const void* g, void* l) {
    __builtin_amdgcn_global_load_lds(
        (const __attribute__((address_space(1))) unsigned int*)g,
        (__attribute__((address_space(3))) unsigned int*)l, 16, 0, 0);
}

// ---------------------------------------------------------------------------
// One 1024-thread block per graph (512 blocks = 2/CU, 32 waves/CU).
//  A: h[i] = feat[i,:]·W + real_i·W[255]  — double-buffered global_load_lds
//     pipeline (T3 2-phase recipe), 1 node per wave per chunk, W in VGPRs.
//  B: deg (col cached as ushort in LDS) -> dinv -> agg (row read)
//  C: tanh score -> float4 rank-count top-K (jax tie-break)
//  D: gated gather-mean into d_out[g, 0:256]
// ---------------------------------------------------------------------------
__global__ __launch_bounds__(1024) void k_fused(const float* __restrict__ feat,
                                                const int*   __restrict__ z,
                                                const int*   __restrict__ ei,
                                                const float* __restrict__ W,
                                                const float* __restrict__ bias,
                                                float*       __restrict__ outp) {
    __shared__ __align__(16) float stage[2][CH_FLOATS]; // 32640 B (A); col cache (B)
    __shared__ __align__(16) float Wl[256];
    __shared__ __align__(16) float score[NPG];
    __shared__ float h_l[NPG];
    __shared__ float dinv_l[NPG];
    __shared__ float agg[NPG];
    __shared__ float realb[NPG];
    __shared__ int   deg[NPG];
    __shared__ int   rank2[2][NPG];
    __shared__ int   selidx[K_KEEP];
    __shared__ float selsc[K_KEEP];
    __shared__ float red[3][256];
    __shared__ int   cnt;

    const int g     = blockIdx.x;
    const int tid   = threadIdx.x;
    const int nbase = g * NPG;
    const int lane  = tid & 63;
    const int wave  = tid >> 6;

    if (tid < 256) Wl[tid] = W[tid];
    if (tid < NPG) {
        realb[tid] = (z[nbase + tid] != 100) ? 1.f : 0.f;
        deg[tid]   = 1;                   // self-loop
        agg[tid]   = 0.f;
    }
    if (tid == 0) cnt = 0;
    __syncthreads();

    // ---------------- Phase A: projection h (2-phase DMA pipeline) ----------
    {
        const float w0   = Wl[lane];
        const float w64  = Wl[lane + 64];
        const float w128 = Wl[lane + 128];
        const float w192 = (lane < 63) ? Wl[lane + 192] : 0.f;
        const float w255 = Wl[FDIM];
        const char* srcb = (const char*)(feat + (size_t)nbase * FDIM);

        // prologue: stage chunk 0
        if (tid < CH_F4)
            lds_dma16(srcb + (size_t)tid * 16, (char*)stage[0] + (size_t)tid * 16);
        asm volatile("s_waitcnt vmcnt(0)" ::: "memory");
        __builtin_amdgcn_s_barrier();
        __builtin_amdgcn_sched_barrier(0);

        for (int ch = 0; ch < NCHUNK; ++ch) {
            const float* cur = stage[ch & 1];
            float*       nxt = (float*)stage[(ch & 1) ^ 1];
            if (ch + 1 < NCHUNK && tid < CH_F4)
                lds_dma16(srcb + (size_t)(ch + 1) * 16320 + (size_t)tid * 16,
                          (char*)nxt + (size_t)tid * 16);

            // dot-product for node = ch*16 + wave
            const float* row = cur + wave * FDIM;
            const float  rb  = realb[ch * CH_NODES + wave];
            float acc = (lane == 0) ? rb * w255 : 0.f;
            acc = fmaf(row[lane],       w0,   acc);
            acc = fmaf(row[lane + 64],  w64,  acc);
            acc = fmaf(row[lane + 128], w128, acc);
            if (lane < 63)
                acc = fmaf(row[lane + 192], w192, acc);
#pragma unroll
            for (int off = 32; off; off >>= 1)
                acc += __shfl_down(acc, off, 64);
            if (lane == 0) h_l[ch * CH_NODES + wave] = acc;

            asm volatile("s_waitcnt vmcnt(0)" ::: "memory"); // next chunk landed
            __builtin_amdgcn_s_barrier();
            __builtin_amdgcn_sched_barrier(0);
        }
    }

    // ---------------- Phase B: degree + aggregation ----------------
    {
        ushort4*    cc4   = (ushort4*)stage;      // local col cache (32 KB)
        const int4* colp4 = (const int4*)(ei + (size_t)E_TOT + (size_t)g * EPG);
        const int4* rowp4 = (const int4*)(ei + (size_t)g * EPG);

#pragma unroll
        for (int it = 0; it < 4; ++it) {
            const int  idx = it * 1024 + tid;
            const int4 c4  = colp4[idx];
            ushort4 u;
            u.x = (unsigned short)(c4.x - nbase);
            u.y = (unsigned short)(c4.y - nbase);
            u.z = (unsigned short)(c4.z - nbase);
            u.w = (unsigned short)(c4.w - nbase);
            cc4[idx] = u;
            atomicAdd(&deg[u.x], 1);
            atomicAdd(&deg[u.y], 1);
            atomicAdd(&deg[u.z], 1);
            atomicAdd(&deg[u.w], 1);
        }
        __syncthreads();

        if (tid < NPG)   // correctly-rounded f32 rsqrt (match np within 1 ulp)
            dinv_l[tid] = (float)(1.0 / sqrt((double)deg[tid]));
        __syncthreads();

#pragma unroll
        for (int it = 0; it < 4; ++it) {
            const int     idx = it * 1024 + tid;
            const int4    r4  = rowp4[idx];
            const ushort4 u   = cc4[idx];
            int r;
            r = r4.x - nbase; atomicAdd(&agg[u.x], dinv_l[r] * dinv_l[u.x] * h_l[r]);
            r = r4.y - nbase; atomicAdd(&agg[u.y], dinv_l[r] * dinv_l[u.y] * h_l[r]);
            r = r4.z - nbase; atomicAdd(&agg[u.z], dinv_l[r] * dinv_l[u.z] * h_l[r]);
            r = r4.w - nbase; atomicAdd(&agg[u.w], dinv_l[r] * dinv_l[u.w] * h_l[r]);
        }
        __syncthreads();
    }

    // ---------------- Phase C: score + top-K selection ----------------
    if (tid < NPG)
        score[tid] = tanhf(agg[tid] + dinv_l[tid] * dinv_l[tid] * h_l[tid] + bias[0]);
    __syncthreads();

    {
        const int    node = tid & (NPG - 1);
        const int    half = tid >> 9;
        const float  sc   = score[node];
        const float4* s4p = (const float4*)&score[half * 256];
        int part = 0;
#pragma unroll 8
        for (int i = 0; i < 64; ++i) {
            const float4 s4 = s4p[i];            // broadcast b128 read
            const int    j  = half * 256 + i * 4;
            part += (s4.x > sc) || (s4.x == sc && (j + 0) < node);
            part += (s4.y > sc) || (s4.y == sc && (j + 1) < node);
            part += (s4.z > sc) || (s4.z == sc && (j + 2) < node);
            part += (s4.w > sc) || (s4.w == sc && (j + 3) < node);
        }
        rank2[half][node] = part;
    }
    __syncthreads();

    if (tid < NPG) {
        const int rank = rank2[0][tid] + rank2[1][tid];
        if (rank < K_KEEP) {                      // jax tie-break: lower idx wins
            const int slot = atomicAdd(&cnt, 1);
            selidx[slot] = tid;
            selsc[slot]  = score[tid];
        }
    }
    __syncthreads();

    // ---------------- Phase D: gated gather-mean ----------------
    {
        const int f = tid & 255;
        const int q = tid >> 8;                   // 4 quarters
        float acc = 0.f;
        if (f < FDIM) {
            const float* fb = feat + (size_t)nbase * FDIM + f;
#pragma unroll 8
            for (int s = q; s < K_KEEP; s += 4)
                acc = fmaf(selsc[s], fb[(size_t)selidx[s] * FDIM], acc);
        } else {
#pragma unroll 8
            for (int s = q; s < K_KEEP; s += 4)
                acc = fmaf(selsc[s], realb[selidx[s]], acc);
        }
        if (q) red[q - 1][f] = acc;
        __syncthreads();
        if (q == 0)
            outp[(size_t)g * 256 + f] =
                (acc + red[0][f] + red[1][f] + red[2][f]) * (1.f / K_KEEP);
    }
}

extern "C" void kernel_launch(void* const* d_in, const int* in_sizes, int n_in,
                              void* d_out, int out_size, void* d_ws, size_t ws_size,
                              hipStream_t stream) {
    const float* feat = (const float*)d_in[0];   // out: [N, F] f32
    const int*   z    = (const int*)  d_in[1];   // z:   [N] i32
    const int*   ei   = (const int*)  d_in[2];   // edge_index: [2, E] i32
    // d_in[3] = batch (unused), d_in[6] = edge_attr (unused)
    const float* W    = (const float*)d_in[4];   // [F+1] f32
    const float* bias = (const float*)d_in[5];   // [1] f32
    float* outp = (float*)d_out;                 // [B, F+1] f32

    k_fused<<<B_GR, 1024, 0, stream>>>(feat, z, ei, W, bias, outp);
}